// Round 2
// baseline (956.796 us; speedup 1.0000x reference)
//
#include <hip/hip_runtime.h>

typedef __bf16 bf16_t;
typedef bf16_t bf16x8 __attribute__((ext_vector_type(8)));
typedef bf16_t bf16x4v __attribute__((ext_vector_type(4)));
typedef float f32x4 __attribute__((ext_vector_type(4)));

// Problem constants
// B=2, S=2048, HID=2048, H=16, Q_LORA=1536, KV_LORA=512, D_NOPE=128, D_ROPE=64, D_V=128, D_QK=192
static constexpr float QSCALE = 0.07216878364870323f * 1.44269504088896341f; // 192^-0.5 * log2(e)

// ---------------- cast fp32 -> bf16 (8 elems/thread) ----------------
__global__ void k_cast_bf16(const float* __restrict__ in, bf16_t* __restrict__ out, int n8) {
  int i = blockIdx.x * 256 + threadIdx.x;
  if (i >= n8) return;
  const float4* p = (const float4*)in + (size_t)i * 2;
  float4 a = p[0], b = p[1];
  bf16x8 o = {(bf16_t)a.x, (bf16_t)a.y, (bf16_t)a.z, (bf16_t)a.w,
              (bf16_t)b.x, (bf16_t)b.y, (bf16_t)b.z, (bf16_t)b.w};
  ((bf16x8*)out)[i] = o;
}

// ---------------- generic bf16 GEMM: C(MxN) = A(MxK) * Bt(NxK)^T ----------------
// 128x128 tile, BK=32, 4 waves (2x2), each wave 64x64 as 4x4 16x16x32 MFMA frags.
// Staging: 256 threads x 16 elems = 4096 = 128x32 per array (2 rows/thread-pair).
__global__ __launch_bounds__(256) void k_gemm(
    const bf16_t* __restrict__ A, const bf16_t* __restrict__ Bt,
    float* __restrict__ C, int M, int N, int K) {
  __shared__ __align__(16) bf16_t As[128][40]; // +8 pad
  __shared__ __align__(16) bf16_t Bs[128][40];
  const int tid = threadIdx.x;
  const int lane = tid & 63, wid = tid >> 6;
  const int wr = wid >> 1, wc = wid & 1;
  const int lr = lane & 15, lk = lane >> 4;
  const int bm = blockIdx.y * 128, bn = blockIdx.x * 128;
  f32x4 acc[4][4] = {};
  const int sr = tid >> 1, scc = (tid & 1) * 16;
  const bf16_t* aSrc = A + (size_t)(bm + sr) * K + scc;
  const bf16_t* bSrc = Bt + (size_t)(bn + sr) * K + scc;
  const bool bValid = (bn + sr) < N;
  for (int kt = 0; kt < K; kt += 32) {
    bf16x8 av0 = *(const bf16x8*)(aSrc + kt);
    bf16x8 av1 = *(const bf16x8*)(aSrc + kt + 8);
    bf16x8 bv0 = {}, bv1 = {};
    if (bValid) {
      bv0 = *(const bf16x8*)(bSrc + kt);
      bv1 = *(const bf16x8*)(bSrc + kt + 8);
    }
    *(bf16x8*)(&As[sr][scc]) = av0;
    *(bf16x8*)(&As[sr][scc + 8]) = av1;
    *(bf16x8*)(&Bs[sr][scc]) = bv0;
    *(bf16x8*)(&Bs[sr][scc + 8]) = bv1;
    __syncthreads();
    bf16x8 af[4], bff[4];
#pragma unroll
    for (int i = 0; i < 4; i++)
      af[i] = *(const bf16x8*)(&As[wr * 64 + i * 16 + lr][lk * 8]);
#pragma unroll
    for (int j = 0; j < 4; j++)
      bff[j] = *(const bf16x8*)(&Bs[wc * 64 + j * 16 + lr][lk * 8]);
#pragma unroll
    for (int i = 0; i < 4; i++)
#pragma unroll
      for (int j = 0; j < 4; j++)
        acc[i][j] = __builtin_amdgcn_mfma_f32_16x16x32_bf16(af[i], bff[j], acc[i][j], 0, 0, 0);
    __syncthreads();
  }
  const int crow = bm + wr * 64 + lk * 4;
  const int ccol = bn + wc * 64 + lr;
#pragma unroll
  for (int i = 0; i < 4; i++)
#pragma unroll
    for (int j = 0; j < 4; j++) {
      int col = ccol + j * 16;
      if (col < N) {
#pragma unroll
        for (int r = 0; r < 4; r++)
          C[(size_t)(crow + i * 16 + r) * N + col] = acc[i][j][r];
      }
    }
}

// ---------------- RMSNorm over 1536 (q_a) -> bf16 ----------------
__global__ __launch_bounds__(256) void k_rms_q(const float* __restrict__ in,
                                               const float* __restrict__ w,
                                               bf16_t* __restrict__ out) {
  int row = blockIdx.x;
  const float4* x4 = (const float4*)(in + (size_t)row * 1536);
  float ss = 0.f;
  for (int i = threadIdx.x; i < 384; i += 256) {
    float4 v = x4[i];
    ss += v.x * v.x + v.y * v.y + v.z * v.z + v.w * v.w;
  }
  for (int m = 32; m; m >>= 1) ss += __shfl_xor(ss, m);
  __shared__ float parts[4];
  if ((threadIdx.x & 63) == 0) parts[threadIdx.x >> 6] = ss;
  __syncthreads();
  float inv = rsqrtf((parts[0] + parts[1] + parts[2] + parts[3]) * (1.f / 1536.f) + 1e-6f);
  const float4* w4 = (const float4*)w;
  for (int i = threadIdx.x; i < 384; i += 256) {
    float4 v = x4[i];
    float4 ww = w4[i];
    bf16x4v o = {(bf16_t)(v.x * inv * ww.x), (bf16_t)(v.y * inv * ww.y),
                 (bf16_t)(v.z * inv * ww.z), (bf16_t)(v.w * inv * ww.w)};
    *(bf16x4v*)(out + (size_t)row * 1536 + i * 4) = o;
  }
}

// ---------------- kv_all row: RMSNorm(512)->kvn, rope(k_pe 64)->K[*][128..191] ----------------
__global__ __launch_bounds__(256) void k_kv_norm_rope(const float* __restrict__ kvall,
                                                      const float* __restrict__ w,
                                                      const float* __restrict__ freqs,
                                                      bf16_t* __restrict__ kvn,
                                                      bf16_t* __restrict__ Kf) {
  int row = blockIdx.x, tid = threadIdx.x;
  int b = row >> 11, s = row & 2047;
  const float* x = kvall + (size_t)row * 576;
  float ss = 0.f;
  float4 v = {0.f, 0.f, 0.f, 0.f};
  if (tid < 128) {
    v = ((const float4*)x)[tid];
    ss = v.x * v.x + v.y * v.y + v.z * v.z + v.w * v.w;
  }
  for (int m = 32; m; m >>= 1) ss += __shfl_xor(ss, m);
  __shared__ float parts[4];
  if ((tid & 63) == 0) parts[tid >> 6] = ss;
  __syncthreads();
  float inv = rsqrtf((parts[0] + parts[1] + parts[2] + parts[3]) * (1.f / 512.f) + 1e-6f);
  if (tid < 128) {
    float4 ww = ((const float4*)w)[tid];
    bf16x4v o = {(bf16_t)(v.x * inv * ww.x), (bf16_t)(v.y * inv * ww.y),
                 (bf16_t)(v.z * inv * ww.z), (bf16_t)(v.w * inv * ww.w)};
    *(bf16x4v*)(kvn + (size_t)row * 512 + tid * 4) = o;
  }
  if (tid < 32) {
    float xr = x[512 + 2 * tid], xi = x[513 + 2 * tid];
    float c = freqs[s * 64 + 2 * tid], sn = freqs[s * 64 + 2 * tid + 1];
    bf16_t o0 = (bf16_t)(xr * c - xi * sn);
    bf16_t o1 = (bf16_t)(xr * sn + xi * c);
#pragma unroll
    for (int h = 0; h < 16; h++) {
      size_t base = ((size_t)(b * 16 + h) * 2048 + s) * 192 + 128 + 2 * tid;
      Kf[base] = o0;
      Kf[base + 1] = o1;
    }
  }
}

// ---------------- q rope + scale: q fp32 [row][3072] -> Q bf16 [b][h][s][192] ----------------
__global__ __launch_bounds__(192) void k_q_rope(const float* __restrict__ q,
                                                const float* __restrict__ freqs,
                                                bf16_t* __restrict__ Q) {
  int row = blockIdx.x;
  int h = blockIdx.y;
  int d = threadIdx.x;
  int b = row >> 11, s = row & 2047;
  const float* src = q + (size_t)row * 3072 + h * 192;
  float val;
  if (d < 128) {
    val = src[d];
  } else {
    int i = (d - 128) >> 1;
    float xr = src[128 + 2 * i], xi = src[129 + 2 * i];
    float c = freqs[s * 64 + 2 * i], sn = freqs[s * 64 + 2 * i + 1];
    val = ((d & 1) == 0) ? (xr * c - xi * sn) : (xr * sn + xi * c);
  }
  Q[((size_t)(b * 16 + h) * 2048 + s) * 192 + d] = (bf16_t)(val * QSCALE);
}

// ---------------- split kv fp32 [row][4096] -> K nope [b][h][s][0..127], Vt [b][h][d][s] ----------------
__global__ __launch_bounds__(256) void k_split_kv(const float* __restrict__ kvfull,
                                                  bf16_t* __restrict__ Kf,
                                                  bf16_t* __restrict__ Vt) {
  __shared__ bf16_t vt_l[128][66];
  int s0 = blockIdx.x * 64; // row tile (rows never straddle batch: 2048 % 64 == 0)
  int h = blockIdx.y;
#pragma unroll 4
  for (int i = 0; i < 32; i++) {
    int idx = i * 256 + threadIdx.x;
    int r = idx >> 7, d = idx & 127;
    int row = s0 + r;
    int b = row >> 11, s = row & 2047;
    const float* src = kvfull + (size_t)row * 4096 + h * 256;
    float kn = src[d], vv = src[128 + d];
    Kf[((size_t)(b * 16 + h) * 2048 + s) * 192 + d] = (bf16_t)kn;
    vt_l[d][r] = (bf16_t)vv;
  }
  __syncthreads();
#pragma unroll 4
  for (int i = 0; i < 32; i++) {
    int idx = i * 256 + threadIdx.x;
    int d = idx >> 6, ss = idx & 63;
    int row = s0 + ss;
    int b = row >> 11, s = row & 2047;
    Vt[((size_t)(b * 16 + h) * 128 + d) * 2048 + s] = vt_l[d][ss];
  }
}

// ---------------- flash attention: 1 wave per 16 q-rows, KBLK=32, causal ----------------
// Q,K: [b*16+h][s][192] bf16 (Q pre-scaled by 192^-.5*log2e); Vt: [b*16+h][d][s]; O: [b*2048+s][h*128+d]
__global__ __launch_bounds__(64) void k_attn(const bf16_t* __restrict__ Q,
                                             const bf16_t* __restrict__ Kf,
                                             const bf16_t* __restrict__ Vt,
                                             bf16_t* __restrict__ O) {
  __shared__ __align__(16) bf16_t P[16][40];
  int qb = blockIdx.x * 16;
  int bh = blockIdx.y;
  int b = bh >> 4, h = bh & 15;
  int lane = threadIdx.x;
  int lr = lane & 15, lk = lane >> 4;
  const bf16_t* Qb = Q + (size_t)bh * 2048 * 192;
  const bf16_t* Kb = Kf + (size_t)bh * 2048 * 192;
  const bf16_t* Vb = Vt + (size_t)bh * 128 * 2048;
  bf16x8 aq[6];
#pragma unroll
  for (int f = 0; f < 6; f++)
    aq[f] = *(const bf16x8*)(Qb + (size_t)(qb + lr) * 192 + f * 32 + lk * 8);
  f32x4 acc[8] = {};
  float m_s[4], l_s[4];
#pragma unroll
  for (int r = 0; r < 4; r++) { m_s[r] = -1e30f; l_s[r] = 0.f; }
  int nkt = (qb + 15) / 32 + 1;
  for (int kt = 0; kt < nkt; kt++) {
    int k0 = kt * 32;
    f32x4 sc[2];
#pragma unroll
    for (int hh = 0; hh < 2; hh++) {
      f32x4 a = {};
      const bf16_t* kr = Kb + (size_t)(k0 + hh * 16 + lr) * 192 + lk * 8;
#pragma unroll
      for (int f = 0; f < 6; f++) {
        bf16x8 bk = *(const bf16x8*)(kr + f * 32);
        a = __builtin_amdgcn_mfma_f32_16x16x32_bf16(aq[f], bk, a, 0, 0, 0);
      }
      sc[hh] = a;
    }
    if (k0 + 31 > qb) { // diagonal tile: apply causal mask
#pragma unroll
      for (int hh = 0; hh < 2; hh++) {
        int key = k0 + hh * 16 + lr;
#pragma unroll
        for (int r = 0; r < 4; r++) {
          int qrow = qb + lk * 4 + r;
          if (key > qrow) sc[hh][r] = -1e30f;
        }
      }
    }
    float alpha[4];
#pragma unroll
    for (int r = 0; r < 4; r++) {
      float v = fmaxf(sc[0][r], sc[1][r]);
      v = fmaxf(v, __shfl_xor(v, 1));
      v = fmaxf(v, __shfl_xor(v, 2));
      v = fmaxf(v, __shfl_xor(v, 4));
      v = fmaxf(v, __shfl_xor(v, 8));
      float mn = fmaxf(m_s[r], v);
      alpha[r] = exp2f(m_s[r] - mn);
      m_s[r] = mn;
      float p0 = exp2f(sc[0][r] - mn);
      float p1 = exp2f(sc[1][r] - mn);
      sc[0][r] = p0;
      sc[1][r] = p1;
      float sm = p0 + p1;
      sm += __shfl_xor(sm, 1);
      sm += __shfl_xor(sm, 2);
      sm += __shfl_xor(sm, 4);
      sm += __shfl_xor(sm, 8);
      l_s[r] = l_s[r] * alpha[r] + sm;
    }
#pragma unroll
    for (int j = 0; j < 8; j++)
#pragma unroll
      for (int r = 0; r < 4; r++) acc[j][r] *= alpha[r];
    __syncthreads(); // WAR: previous iter's P reads done before overwrite
#pragma unroll
    for (int r = 0; r < 4; r++) {
      P[lk * 4 + r][lr] = (bf16_t)sc[0][r];
      P[lk * 4 + r][16 + lr] = (bf16_t)sc[1][r];
    }
    __syncthreads(); // RAW: P visible before fragment read
    bf16x8 pa = *(const bf16x8*)(&P[lr][lk * 8]);
    const bf16_t* vr = Vb + (size_t)lr * 2048 + k0 + lk * 8;
#pragma unroll
    for (int j = 0; j < 8; j++) {
      bf16x8 bv = *(const bf16x8*)(vr + (size_t)j * 16 * 2048);
      acc[j] = __builtin_amdgcn_mfma_f32_16x16x32_bf16(pa, bv, acc[j], 0, 0, 0);
    }
  }
#pragma unroll
  for (int r = 0; r < 4; r++) l_s[r] = 1.f / l_s[r];
  size_t orow = (size_t)b * 2048 + qb + lk * 4;
#pragma unroll
  for (int j = 0; j < 8; j++)
#pragma unroll
    for (int r = 0; r < 4; r++)
      O[(orow + r) * 2048 + h * 128 + j * 16 + lr] = (bf16_t)(acc[j][r] * l_s[r]);
}

extern "C" void kernel_launch(void* const* d_in, const int* in_sizes, int n_in,
                              void* d_out, int out_size, void* d_ws, size_t ws_size,
                              hipStream_t stream) {
  const float* x = (const float*)d_in[0];
  const float* freqs = (const float*)d_in[1];
  const float* wq_a = (const float*)d_in[2];
  const float* q_norm_w = (const float*)d_in[3];
  const float* wq_b = (const float*)d_in[4];
  const float* wkv_a = (const float*)d_in[5];
  const float* kv_norm_w = (const float*)d_in[6];
  const float* wkv_b = (const float*)d_in[7];
  const float* wo = (const float*)d_in[8];
  float* out = (float*)d_out;
  char* ws = (char*)d_ws;

  // fp32 scratch (64MB region) time-shared: kv_all -> kv_full -> q_a -> q
  float* f32scr = (float*)(ws);
  bf16_t* xbf = (bf16_t*)(ws + 67108864);
  bf16_t* wqab = (bf16_t*)(ws + 83886080);
  bf16_t* wqbb = (bf16_t*)(ws + 90177536);
  bf16_t* wkvab = (bf16_t*)(ws + 99614720);
  bf16_t* wkvbb = (bf16_t*)(ws + 101974016);
  bf16_t* wob = (bf16_t*)(ws + 106168320);
  bf16_t* qan = (bf16_t*)(ws + 114556928);
  bf16_t* kvn = (bf16_t*)(ws + 127139840);
  bf16_t* Qb = (bf16_t*)(ws + 131334144);
  bf16_t* Kb = (bf16_t*)(ws + 156499968);
  bf16_t* Vtb = (bf16_t*)(ws + 181665792);
  bf16_t* aob = (bf16_t*)(ws + 198443008);
  (void)in_sizes; (void)n_in; (void)out_size; (void)ws_size;

  auto cast = [&](const float* src, bf16_t* dst, int n) {
    int n8 = n / 8;
    k_cast_bf16<<<(n8 + 255) / 256, 256, 0, stream>>>(src, dst, n8);
  };
  cast(x, xbf, 8388608);
  cast(wq_a, wqab, 3145728);
  cast(wq_b, wqbb, 4718592);
  cast(wkv_a, wkvab, 1179648);
  cast(wkv_b, wkvbb, 2097152);
  cast(wo, wob, 4194304);

  // KV branch
  k_gemm<<<dim3(5, 32), 256, 0, stream>>>(xbf, wkvab, f32scr, 4096, 576, 2048);
  k_kv_norm_rope<<<4096, 256, 0, stream>>>(f32scr, kv_norm_w, freqs, kvn, Kb);
  k_gemm<<<dim3(32, 32), 256, 0, stream>>>(kvn, wkvbb, f32scr, 4096, 4096, 512);
  k_split_kv<<<dim3(64, 16), 256, 0, stream>>>(f32scr, Kb, Vtb);
  // Q branch
  k_gemm<<<dim3(12, 32), 256, 0, stream>>>(xbf, wqab, f32scr, 4096, 1536, 2048);
  k_rms_q<<<4096, 256, 0, stream>>>(f32scr, q_norm_w, qan);
  k_gemm<<<dim3(24, 32), 256, 0, stream>>>(qan, wqbb, f32scr, 4096, 3072, 1536);
  k_q_rope<<<dim3(4096, 16), 192, 0, stream>>>(f32scr, freqs, Qb);
  // Attention
  k_attn<<<dim3(128, 32), 64, 0, stream>>>(Qb, Kb, Vtb, aob);
  // Output projection -> d_out (fp32)
  k_gemm<<<dim3(16, 32), 256, 0, stream>>>(aob, wob, out, 4096, 2048, 2048);
}